// Round 4
// baseline (1174.478 us; speedup 1.0000x reference)
//
#include <hip/hip_runtime.h>

// SPDnet autoencoder, collapsed analytically:
//   out_b = D (E x_b E^T - EPS*I16) D^T + EPS*I128
// where E = Wenc2*Wenc1*Wenc0 (16x128), D = Wdec2*Wdec1*Wdec0 (128x16).
// Valid because: encoder ReEigs are no-ops (lambda_min >= 0.01 by interlacing),
// LogEig->ExpEig->ReEig is the identity, and decoder ReEigs clamp exactly the
// rank-deficient null space: reeig(W X W^T) = W X W^T + EPS*(I - W W^T) when
// all eig(X) >= EPS and W has orthonormal columns.
//
// R4 == R3 resubmit (R3 bench died to a container infra failure; source
// re-audited for alignment/races/OOB — clean).
//
// R3: LDS-pipe offload. R2 was LDS-return-BW bound (~290k LDS cycles/CU:
// uniform E b128 reads in stage 1, scalar Dt/u reads in stage 4). Now:
//  - E/D are read from GLOBAL (wsE/wsEt/wsD/wsDt in workspace): wave-uniform
//    stage-1 E reads go to the scalar cache, per-lane E/D reads are L1/L2
//    resident VMEM — both pipes were idle.
//  - stage 4 register-blocked 8x4 (x2 col passes): u kept transposed in LDS
//    (ut[m][p]) so per-m u-slices are 2 conflict-free ds_read_b128.
//    LDS instr/wave: 512 -> 64.
//  - stage 2 reads t1 as f4 (stride-132 rows keep i-groups on disjoint banks).
//  - NT stores reverted (R2 showed 2x write amplification from L2 bypass).
// FP accumulation order identical to R2 (same operand order per output).

#define SPD_EPS 1e-4f

typedef float f32x4 __attribute__((ext_vector_type(4)));

// ---------------- setup: E/D products in all needed orientations ------------
// 16 blocks: each redundantly computes e1/d1, then block bi writes E row bi
// (to wsE and wsEt) and D rows [8bi, 8bi+8) (to wsD and wsDt).
__global__ __launch_bounds__(256) void setup_ED(
    const float* __restrict__ wenc0,  // 64x128
    const float* __restrict__ wenc1,  // 32x64
    const float* __restrict__ wenc2,  // 16x32
    const float* __restrict__ wdec0,  // 32x16
    const float* __restrict__ wdec1,  // 64x32
    const float* __restrict__ wdec2,  // 128x64
    float* __restrict__ wsE,          // 16x128  E row-major
    float* __restrict__ wsEt,         // 128x16  E^T row-major
    float* __restrict__ wsD,          // 128x16  D row-major
    float* __restrict__ wsDt)         // 16x128  D^T row-major
{
    __shared__ float e1[16 * 64];   // Wenc2 @ Wenc1
    __shared__ float d1[64 * 16];   // Wdec1 @ Wdec0
    const int t = threadIdx.x;
    const int bi = blockIdx.x;      // 0..15

    for (int r = 0; r < 4; ++r) {
        int o = t + 256 * r;
        int i = o >> 6, j = o & 63;
        float acc = 0.f;
        for (int k = 0; k < 32; ++k) acc += wenc2[i * 32 + k] * wenc1[k * 64 + j];
        e1[o] = acc;
    }
    for (int r = 0; r < 4; ++r) {
        int o = t + 256 * r;
        int p = o >> 4, m = o & 15;
        float acc = 0.f;
        for (int k = 0; k < 32; ++k) acc += wdec1[p * 32 + k] * wdec0[k * 16 + m];
        d1[o] = acc;
    }
    __syncthreads();

    if (t < 128) {
        // E[bi][t]
        float acc = 0.f;
        for (int k = 0; k < 64; ++k) acc += e1[bi * 64 + k] * wenc0[k * 128 + t];
        wsE[bi * 128 + t] = acc;
        wsEt[t * 16 + bi] = acc;
    } else {
        // D[p][m], p in [8bi, 8bi+8)
        int u0 = t - 128;
        int p = bi * 8 + (u0 >> 4), m = u0 & 15;
        float acc = 0.f;
        for (int k = 0; k < 64; ++k) acc += wdec2[p * 64 + k] * d1[k * 16 + m];
        wsD[p * 16 + m] = acc;
        wsDt[m * 128 + p] = acc;
    }
}

// ---------------- main: one block = 2 batch elements -------------------------
// 512 threads: sub = t>>8 picks the batch element, tl = t&255 per-element tid.
//
// LDS per sub (floats): buf 2112 (t1[16][132] then reused as ut[16][132]),
// s 256. Total 2*2368 = 4736 floats = 18.9 KB -> wave-slot-limited at
// 4 blocks/CU (32 waves). E/D matrices live in global only (L1/L2/sK$).
__global__ __launch_bounds__(512, 8) void spdnet_main(
    const float* __restrict__ x,     // B x 128 x 128
    const float* __restrict__ wsE,   // 16x128
    const float* __restrict__ wsEt,  // 128x16
    const float* __restrict__ wsD,   // 128x16
    const float* __restrict__ wsDt,  // 16x128
    float* __restrict__ out)         // B x 128 x 128
{
    __shared__ __align__(16) float smem[2 * 2368];
    const int t = threadIdx.x;
    const int sub = t >> 8;
    const int tl = t & 255;
    float* buf = smem + sub * 2368;  // t1 / ut, row stride 132 (528B, 16B-mult)
    float* s   = buf + 2112;         // 16x16

    const int b = blockIdx.x * 2 + sub;
    const float* xb = x + (size_t)b * 16384;
    float* ob = out + (size_t)b * 16384;

    // ---- stage 1: t1 = E @ x_b (16x128), K-split 2-way, x read ONCE ---------
    // column j per thread (coalesced 256B/wave per k); E column k is a
    // wave-UNIFORM global read from wsEt (scalar-cache path, not LDS).
    {
        const int j = tl & 127;
        const int h = tl >> 7;
        const int k0 = h << 6;
        const float* xcol = xb + (size_t)k0 * 128 + j;
        const f32x4* et = (const f32x4*)(wsEt + k0 * 16);
        float acc[16];
#pragma unroll
        for (int ii = 0; ii < 16; ++ii) acc[ii] = 0.f;

#pragma unroll 4
        for (int k = 0; k < 64; ++k) {
            float xv = xcol[k * 128];
            f32x4 e0 = et[k * 4 + 0];
            f32x4 e1v = et[k * 4 + 1];
            f32x4 e2 = et[k * 4 + 2];
            f32x4 e3 = et[k * 4 + 3];
            acc[0]  += e0.x  * xv; acc[1]  += e0.y  * xv;
            acc[2]  += e0.z  * xv; acc[3]  += e0.w  * xv;
            acc[4]  += e1v.x * xv; acc[5]  += e1v.y * xv;
            acc[6]  += e1v.z * xv; acc[7]  += e1v.w * xv;
            acc[8]  += e2.x  * xv; acc[9]  += e2.y  * xv;
            acc[10] += e2.z  * xv; acc[11] += e2.w  * xv;
            acc[12] += e3.x  * xv; acc[13] += e3.y  * xv;
            acc[14] += e3.z  * xv; acc[15] += e3.w  * xv;
        }
        float* t1 = buf;
        if (h == 0) {
#pragma unroll
            for (int ii = 0; ii < 16; ++ii) t1[ii * 132 + j] = acc[ii];
        }
        __syncthreads();
        if (h == 1) {
#pragma unroll
            for (int ii = 0; ii < 16; ++ii) t1[ii * 132 + j] += acc[ii];
        }
    }
    __syncthreads();

    // ---- stage 2: s = t1 @ E^T - EPS*I (16x16) ------------------------------
    // t1 row as f4 LDS (4 i-groups/wave on disjoint bank-quads: stride 132);
    // E row m as f4 GLOBAL (L1/L2-resident). Accumulation order == R2 (jj asc).
    {
        const int i = tl >> 4, m = tl & 15;
        const f32x4* t1r = (const f32x4*)(buf + i * 132);
        const f32x4* erow = (const f32x4*)(wsE + m * 128);
        float accs = 0.f;
#pragma unroll
        for (int q = 0; q < 32; ++q) {
            f32x4 a = t1r[q];
            f32x4 e = erow[q];
            accs += a.x * e.x;
            accs += a.y * e.y;
            accs += a.z * e.z;
            accs += a.w * e.w;
        }
        if (i == m) accs -= SPD_EPS;
        s[i * 16 + m] = accs;
    }
    __syncthreads();

    // ---- stage 3: u = D @ s, stored TRANSPOSED: ut[m][p] --------------------
    // D row p from global (coalesced f4); s slices are broadcast b128 reads.
    {
        const int p = tl & 127;
        const int hh = tl >> 7;         // owns m in [8hh, 8hh+8)
        const f32x4* drow = (const f32x4*)(wsD + p * 16);
        f32x4 dq0 = drow[0], dq1 = drow[1], dq2 = drow[2], dq3 = drow[3];
        const float* sc = s + 8 * hh;
        float accu[8];
#pragma unroll
        for (int r = 0; r < 8; ++r) accu[r] = 0.f;
#pragma unroll
        for (int i = 0; i < 16; ++i) {
            float dv = (i < 4) ? dq0[i & 3]
                     : (i < 8) ? dq1[i & 3]
                     : (i < 12) ? dq2[i & 3] : dq3[i & 3];
            f32x4 s0 = *(const f32x4*)(sc + i * 16);
            f32x4 s1 = *(const f32x4*)(sc + i * 16 + 4);
            accu[0] += dv * s0.x; accu[1] += dv * s0.y;
            accu[2] += dv * s0.z; accu[3] += dv * s0.w;
            accu[4] += dv * s1.x; accu[5] += dv * s1.y;
            accu[6] += dv * s1.z; accu[7] += dv * s1.w;
        }
        float* ut = buf;                // overwrites t1 (dead after stage 2)
#pragma unroll
        for (int r = 0; r < 8; ++r) ut[(8 * hh + r) * 132 + p] = accu[r];
    }
    __syncthreads();

    // ---- stage 4: out = u @ D^T + EPS*I, register-blocked 8x4 x2 ------------
    // thread (rg = tl>>4, cg = tl&15): rows [8rg,8rg+8), cols 4cg..+3 then
    // 64+4cg..+3. Per m: 1 global f4 of D^T (L1) + 2 conflict-free b128 of ut
    // (banks 4m+8rg+{0..7}, rg-groups disjoint). 64 LDS instr/wave total.
    {
        const int rg = tl >> 4;
        const int cg = tl & 15;
        const int p0 = rg * 8;
        for (int half = 0; half < 2; ++half) {
            const int c0 = half * 64 + cg * 4;
            f32x4 acc8[8];
#pragma unroll
            for (int r = 0; r < 8; ++r) acc8[r] = (f32x4){0.f, 0.f, 0.f, 0.f};
#pragma unroll
            for (int m = 0; m < 16; ++m) {
                f32x4 d4 = *(const f32x4*)(wsDt + m * 128 + c0);
                f32x4 ua = *(const f32x4*)(buf + m * 132 + p0);
                f32x4 ub = *(const f32x4*)(buf + m * 132 + p0 + 4);
                acc8[0] += ua.x * d4;
                acc8[1] += ua.y * d4;
                acc8[2] += ua.z * d4;
                acc8[3] += ua.w * d4;
                acc8[4] += ub.x * d4;
                acc8[5] += ub.y * d4;
                acc8[6] += ub.z * d4;
                acc8[7] += ub.w * d4;
            }
#pragma unroll
            for (int r = 0; r < 8; ++r) {
                int p = p0 + r;
                f32x4 v = acc8[r];
                int d = p - c0;
                if (d >= 0 && d < 4) v[d] += SPD_EPS;
                *(f32x4*)(ob + p * 128 + c0) = v;
            }
        }
    }
}

extern "C" void kernel_launch(void* const* d_in, const int* in_sizes, int n_in,
                              void* d_out, int out_size, void* d_ws, size_t ws_size,
                              hipStream_t stream) {
    const float* x     = (const float*)d_in[0];
    const float* wenc0 = (const float*)d_in[1];
    const float* wenc1 = (const float*)d_in[2];
    const float* wenc2 = (const float*)d_in[3];
    const float* wdec0 = (const float*)d_in[4];
    const float* wdec1 = (const float*)d_in[5];
    const float* wdec2 = (const float*)d_in[6];
    float* out = (float*)d_out;

    float* wsE  = (float*)d_ws;         // 2048 floats
    float* wsEt = wsE + 2048;           // 2048 floats
    float* wsD  = wsEt + 2048;          // 2048 floats
    float* wsDt = wsD + 2048;           // 2048 floats (32 KB total)

    const int B = in_sizes[0] / 16384;  // 2048 (even)

    setup_ED<<<16, 256, 0, stream>>>(wenc0, wenc1, wenc2, wdec0, wdec1, wdec2,
                                     wsE, wsEt, wsD, wsDt);
    spdnet_main<<<B / 2, 512, 0, stream>>>(x, wsE, wsEt, wsD, wsDt, out);
}

// Round 5
// 1077.874 us; speedup vs baseline: 1.0896x; 1.0896x over previous
//
#include <hip/hip_runtime.h>

// SPDnet autoencoder, collapsed analytically:
//   out_b = D (E x_b E^T - EPS*I16) D^T + EPS*I128
// where E = Wenc2*Wenc1*Wenc0 (16x128), D = Wdec2*Wdec1*Wdec0 (128x16).
// Valid because: encoder ReEigs are no-ops (lambda_min >= 0.01 by interlacing),
// LogEig->ExpEig->ReEig is the identity, and decoder ReEigs clamp exactly the
// rank-deficient null space: reeig(W X W^T) = W X W^T + EPS*(I - W W^T) when
// all eig(X) >= EPS and W has orthonormal columns.
//
// R5: spill fix. R4's counters showed a scratch-spill catastrophe: ~1.2 GB of
// SYMMETRIC extra fetch+write (spill/fill), VALUBusy 2.7%, VGPR_Count 32.
// __launch_bounds__(512, 8) had squeezed the allocator to 32 VGPRs since R1,
// while stage 1 (acc[16] + E operands) and stage 4 (8x f32x4 acc) need ~50-60
// live VGPRs -> accumulators spilled inside the inner loops. Fix: relax to
// __launch_bounds__(512, 4) (64-128 VGPR budget, no spill). 16 waves/CU is
// still enough TLP for HBM (16 waves x 4 outstanding 256B loads ≈ 43 GB/s/CU
// available vs 24.6 needed). Structure otherwise identical to R4:
//  - stage 1 reads x once, coalesced, K-split across halves; E via wsEt from
//    global (uniform address -> scalar/L1 path, LDS pipe untouched).
//  - stage 4 register-blocked 8x4x2; u transposed in LDS, conflict-free b128.
//  - plain f4 stores (write-combining through L2).

#define SPD_EPS 1e-4f

typedef float f32x4 __attribute__((ext_vector_type(4)));

// ---------------- setup: E/D products in all needed orientations ------------
// 16 blocks: each redundantly computes e1/d1, then block bi writes E row bi
// (to wsE and wsEt) and D rows [8bi, 8bi+8) (to wsD and wsDt).
__global__ __launch_bounds__(256) void setup_ED(
    const float* __restrict__ wenc0,  // 64x128
    const float* __restrict__ wenc1,  // 32x64
    const float* __restrict__ wenc2,  // 16x32
    const float* __restrict__ wdec0,  // 32x16
    const float* __restrict__ wdec1,  // 64x32
    const float* __restrict__ wdec2,  // 128x64
    float* __restrict__ wsE,          // 16x128  E row-major
    float* __restrict__ wsEt,         // 128x16  E^T row-major
    float* __restrict__ wsD,          // 128x16  D row-major
    float* __restrict__ wsDt)         // 16x128  D^T row-major
{
    __shared__ float e1[16 * 64];   // Wenc2 @ Wenc1
    __shared__ float d1[64 * 16];   // Wdec1 @ Wdec0
    const int t = threadIdx.x;
    const int bi = blockIdx.x;      // 0..15

    for (int r = 0; r < 4; ++r) {
        int o = t + 256 * r;
        int i = o >> 6, j = o & 63;
        float acc = 0.f;
        for (int k = 0; k < 32; ++k) acc += wenc2[i * 32 + k] * wenc1[k * 64 + j];
        e1[o] = acc;
    }
    for (int r = 0; r < 4; ++r) {
        int o = t + 256 * r;
        int p = o >> 4, m = o & 15;
        float acc = 0.f;
        for (int k = 0; k < 32; ++k) acc += wdec1[p * 32 + k] * wdec0[k * 16 + m];
        d1[o] = acc;
    }
    __syncthreads();

    if (t < 128) {
        // E[bi][t]
        float acc = 0.f;
        for (int k = 0; k < 64; ++k) acc += e1[bi * 64 + k] * wenc0[k * 128 + t];
        wsE[bi * 128 + t] = acc;
        wsEt[t * 16 + bi] = acc;
    } else {
        // D[p][m], p in [8bi, 8bi+8)
        int u0 = t - 128;
        int p = bi * 8 + (u0 >> 4), m = u0 & 15;
        float acc = 0.f;
        for (int k = 0; k < 64; ++k) acc += wdec2[p * 64 + k] * d1[k * 16 + m];
        wsD[p * 16 + m] = acc;
        wsDt[m * 128 + p] = acc;
    }
}

// ---------------- main: one block = 2 batch elements -------------------------
// 512 threads: sub = t>>8 picks the batch element, tl = t&255 per-element tid.
//
// LDS per sub (floats): buf 2112 (t1[16][132] then reused as ut[16][132]),
// s 256. Total 2*2368 = 4736 floats = 18.9 KB. E/D matrices live in global
// only (scalar-K$ / L1 / L2).
__global__ __launch_bounds__(512, 4) void spdnet_main(
    const float* __restrict__ x,     // B x 128 x 128
    const float* __restrict__ wsE,   // 16x128
    const float* __restrict__ wsEt,  // 128x16
    const float* __restrict__ wsD,   // 128x16
    const float* __restrict__ wsDt,  // 16x128
    float* __restrict__ out)         // B x 128 x 128
{
    __shared__ __align__(16) float smem[2 * 2368];
    const int t = threadIdx.x;
    const int sub = t >> 8;
    const int tl = t & 255;
    float* buf = smem + sub * 2368;  // t1 / ut, row stride 132 (528B, 16B-mult)
    float* s   = buf + 2112;         // 16x16

    const int b = blockIdx.x * 2 + sub;
    const float* xb = x + (size_t)b * 16384;
    float* ob = out + (size_t)b * 16384;

    // ---- stage 1: t1 = E @ x_b (16x128), K-split 2-way, x read ONCE ---------
    // column j per thread (coalesced 256B/wave per k); E column k is a
    // wave-UNIFORM global read from wsEt (scalar/L1 path, not LDS).
    {
        const int j = tl & 127;
        const int h = tl >> 7;
        const int k0 = h << 6;
        const float* xcol = xb + (size_t)k0 * 128 + j;
        const f32x4* et = (const f32x4*)(wsEt + k0 * 16);
        float acc[16];
#pragma unroll
        for (int ii = 0; ii < 16; ++ii) acc[ii] = 0.f;

#pragma unroll 4
        for (int k = 0; k < 64; ++k) {
            float xv = xcol[k * 128];
            f32x4 e0 = et[k * 4 + 0];
            f32x4 e1v = et[k * 4 + 1];
            f32x4 e2 = et[k * 4 + 2];
            f32x4 e3 = et[k * 4 + 3];
            acc[0]  += e0.x  * xv; acc[1]  += e0.y  * xv;
            acc[2]  += e0.z  * xv; acc[3]  += e0.w  * xv;
            acc[4]  += e1v.x * xv; acc[5]  += e1v.y * xv;
            acc[6]  += e1v.z * xv; acc[7]  += e1v.w * xv;
            acc[8]  += e2.x  * xv; acc[9]  += e2.y  * xv;
            acc[10] += e2.z  * xv; acc[11] += e2.w  * xv;
            acc[12] += e3.x  * xv; acc[13] += e3.y  * xv;
            acc[14] += e3.z  * xv; acc[15] += e3.w  * xv;
        }
        float* t1 = buf;
        if (h == 0) {
#pragma unroll
            for (int ii = 0; ii < 16; ++ii) t1[ii * 132 + j] = acc[ii];
        }
        __syncthreads();
        if (h == 1) {
#pragma unroll
            for (int ii = 0; ii < 16; ++ii) t1[ii * 132 + j] += acc[ii];
        }
    }
    __syncthreads();

    // ---- stage 2: s = t1 @ E^T - EPS*I (16x16) ------------------------------
    // t1 row as f4 LDS (4 i-groups/wave on disjoint bank-quads: stride 132);
    // E row m as f4 GLOBAL (L1/L2-resident). Accumulation order == R2 (jj asc).
    {
        const int i = tl >> 4, m = tl & 15;
        const f32x4* t1r = (const f32x4*)(buf + i * 132);
        const f32x4* erow = (const f32x4*)(wsE + m * 128);
        float accs = 0.f;
#pragma unroll
        for (int q = 0; q < 32; ++q) {
            f32x4 a = t1r[q];
            f32x4 e = erow[q];
            accs += a.x * e.x;
            accs += a.y * e.y;
            accs += a.z * e.z;
            accs += a.w * e.w;
        }
        if (i == m) accs -= SPD_EPS;
        s[i * 16 + m] = accs;
    }
    __syncthreads();

    // ---- stage 3: u = D @ s, stored TRANSPOSED: ut[m][p] --------------------
    // D row p from global (coalesced f4); s slices are broadcast b128 reads.
    {
        const int p = tl & 127;
        const int hh = tl >> 7;         // owns m in [8hh, 8hh+8)
        const f32x4* drow = (const f32x4*)(wsD + p * 16);
        f32x4 dq0 = drow[0], dq1 = drow[1], dq2 = drow[2], dq3 = drow[3];
        const float* sc = s + 8 * hh;
        float accu[8];
#pragma unroll
        for (int r = 0; r < 8; ++r) accu[r] = 0.f;
#pragma unroll
        for (int i = 0; i < 16; ++i) {
            float dv = (i < 4) ? dq0[i & 3]
                     : (i < 8) ? dq1[i & 3]
                     : (i < 12) ? dq2[i & 3] : dq3[i & 3];
            f32x4 s0 = *(const f32x4*)(sc + i * 16);
            f32x4 s1 = *(const f32x4*)(sc + i * 16 + 4);
            accu[0] += dv * s0.x; accu[1] += dv * s0.y;
            accu[2] += dv * s0.z; accu[3] += dv * s0.w;
            accu[4] += dv * s1.x; accu[5] += dv * s1.y;
            accu[6] += dv * s1.z; accu[7] += dv * s1.w;
        }
        float* ut = buf;                // overwrites t1 (dead after stage 2)
#pragma unroll
        for (int r = 0; r < 8; ++r) ut[(8 * hh + r) * 132 + p] = accu[r];
    }
    __syncthreads();

    // ---- stage 4: out = u @ D^T + EPS*I, register-blocked 8x4 x2 ------------
    // thread (rg = tl>>4, cg = tl&15): rows [8rg,8rg+8), cols 4cg..+3 then
    // 64+4cg..+3. Per m: 1 global f4 of D^T (L1) + 2 conflict-free b128 of ut
    // (banks 4m+8rg+{0..7}, rg-groups disjoint). 64 LDS instr/wave total.
    {
        const int rg = tl >> 4;
        const int cg = tl & 15;
        const int p0 = rg * 8;
        for (int half = 0; half < 2; ++half) {
            const int c0 = half * 64 + cg * 4;
            f32x4 acc8[8];
#pragma unroll
            for (int r = 0; r < 8; ++r) acc8[r] = (f32x4){0.f, 0.f, 0.f, 0.f};
#pragma unroll
            for (int m = 0; m < 16; ++m) {
                f32x4 d4 = *(const f32x4*)(wsDt + m * 128 + c0);
                f32x4 ua = *(const f32x4*)(buf + m * 132 + p0);
                f32x4 ub = *(const f32x4*)(buf + m * 132 + p0 + 4);
                acc8[0] += ua.x * d4;
                acc8[1] += ua.y * d4;
                acc8[2] += ua.z * d4;
                acc8[3] += ua.w * d4;
                acc8[4] += ub.x * d4;
                acc8[5] += ub.y * d4;
                acc8[6] += ub.z * d4;
                acc8[7] += ub.w * d4;
            }
#pragma unroll
            for (int r = 0; r < 8; ++r) {
                int p = p0 + r;
                f32x4 v = acc8[r];
                int d = p - c0;
                if (d >= 0 && d < 4) v[d] += SPD_EPS;
                *(f32x4*)(ob + p * 128 + c0) = v;
            }
        }
    }
}

extern "C" void kernel_launch(void* const* d_in, const int* in_sizes, int n_in,
                              void* d_out, int out_size, void* d_ws, size_t ws_size,
                              hipStream_t stream) {
    const float* x     = (const float*)d_in[0];
    const float* wenc0 = (const float*)d_in[1];
    const float* wenc1 = (const float*)d_in[2];
    const float* wenc2 = (const float*)d_in[3];
    const float* wdec0 = (const float*)d_in[4];
    const float* wdec1 = (const float*)d_in[5];
    const float* wdec2 = (const float*)d_in[6];
    float* out = (float*)d_out;

    float* wsE  = (float*)d_ws;         // 2048 floats
    float* wsEt = wsE + 2048;           // 2048 floats
    float* wsD  = wsEt + 2048;          // 2048 floats
    float* wsDt = wsD + 2048;           // 2048 floats (32 KB total)

    const int B = in_sizes[0] / 16384;  // 2048 (even)

    setup_ED<<<16, 256, 0, stream>>>(wenc0, wenc1, wenc2, wdec0, wdec1, wdec2,
                                     wsE, wsEt, wsD, wsDt);
    spdnet_main<<<B / 2, 512, 0, stream>>>(x, wsE, wsEt, wsD, wsDt, out);
}

// Round 6
// 284.739 us; speedup vs baseline: 4.1248x; 3.7855x over previous
//
#include <hip/hip_runtime.h>

// SPDnet autoencoder, collapsed analytically:
//   out_b = D (E x_b E^T - EPS*I16) D^T + EPS*I128
// where E = Wenc2*Wenc1*Wenc0 (16x128), D = Wdec2*Wdec1*Wdec0 (128x16).
// Valid because: encoder ReEigs are no-ops (lambda_min >= 0.01 by interlacing),
// LogEig->ExpEig->ReEig is the identity, and decoder ReEigs clamp exactly the
// rank-deficient null space: reeig(W X W^T) = W X W^T + EPS*(I - W W^T) when
// all eig(X) >= EPS and W has orthonormal columns.
//
// R6: anti-spill restructure. R4/R5 counters showed ~1 GB SYMMETRIC extra
// fetch+write = scratch spill/fill (VALUBusy ~3%) caused by long-latency
// global E/D loads inside unrolled hot loops. R2 showed the LDS-pipe bound
// (~284k LDS-cyc/CU). This version attacks both:
//  - stage 1: thread = (4-row group, f4 col) computes a 4x16 tile over ALL k:
//    per k = 1 global f4 (x, coalesced) + 1 LDS b128 broadcast (E^T). 16-reg
//    accumulator, no k-split merge. LDS instrs halved vs R2, pressure ~40 regs.
//  - E^T in LDS (broadcast operand); E rows / D / D^T read from GLOBAL
//    (L1/L2-resident, VMEM pipe) in unroll-capped short loops.
//  - stage 4: 8x4 register tile x4 col passes; ut b128 reads 2-way aliased
//    (free); Dt operand from global.
//  - 256 thr/block, 2 elements/block, plain __launch_bounds__(256) (R0's
//    proven-safe allocator config). LDS 27.1 KB -> 6 blocks/CU. Grid 1024.

#define SPD_EPS 1e-4f

typedef float f32x4 __attribute__((ext_vector_type(4)));

// ---------------- setup: E/D products in all needed orientations ------------
__global__ __launch_bounds__(256) void setup_ED(
    const float* __restrict__ wenc0,  // 64x128
    const float* __restrict__ wenc1,  // 32x64
    const float* __restrict__ wenc2,  // 16x32
    const float* __restrict__ wdec0,  // 32x16
    const float* __restrict__ wdec1,  // 64x32
    const float* __restrict__ wdec2,  // 128x64
    float* __restrict__ wsE,          // 16x128  E row-major
    float* __restrict__ wsEt,         // 128x16  E^T row-major
    float* __restrict__ wsD,          // 128x16  D row-major
    float* __restrict__ wsDt)         // 16x128  D^T row-major
{
    __shared__ float e1[16 * 64];   // Wenc2 @ Wenc1
    __shared__ float d1[64 * 16];   // Wdec1 @ Wdec0
    const int t = threadIdx.x;
    const int bi = blockIdx.x;      // 0..15

    for (int r = 0; r < 4; ++r) {
        int o = t + 256 * r;
        int i = o >> 6, j = o & 63;
        float acc = 0.f;
        for (int k = 0; k < 32; ++k) acc += wenc2[i * 32 + k] * wenc1[k * 64 + j];
        e1[o] = acc;
    }
    for (int r = 0; r < 4; ++r) {
        int o = t + 256 * r;
        int p = o >> 4, m = o & 15;
        float acc = 0.f;
        for (int k = 0; k < 32; ++k) acc += wdec1[p * 32 + k] * wdec0[k * 16 + m];
        d1[o] = acc;
    }
    __syncthreads();

    if (t < 128) {
        float acc = 0.f;
        for (int k = 0; k < 64; ++k) acc += e1[bi * 64 + k] * wenc0[k * 128 + t];
        wsE[bi * 128 + t] = acc;
        wsEt[t * 16 + bi] = acc;
    } else {
        int u0 = t - 128;
        int p = bi * 8 + (u0 >> 4), m = u0 & 15;
        float acc = 0.f;
        for (int k = 0; k < 64; ++k) acc += wdec2[p * 64 + k] * d1[k * 16 + m];
        wsD[p * 16 + m] = acc;
        wsDt[m * 128 + p] = acc;
    }
}

// ---------------- main: one block = 2 batch elements, 128 threads each -------
// LDS (floats): Et[128*16]=2048 shared; per element: t1[16][132]=2112 (reused
// as ut[16][132]) + s[16][16]=256. Total 2048 + 2*2368 = 6784 fl = 27136 B
// -> 6 blocks/CU (162.8 KB of 160 KiB pool), 24 waves/CU.
__global__ __launch_bounds__(256) void spdnet_main(
    const float* __restrict__ x,     // B x 128 x 128
    const float* __restrict__ wsE,   // 16x128
    const float* __restrict__ wsEt,  // 128x16
    const float* __restrict__ wsD,   // 128x16
    const float* __restrict__ wsDt,  // 16x128
    float* __restrict__ out)         // B x 128 x 128
{
    __shared__ __align__(16) float smem[2048 + 2 * 2368];
    float* Et = smem;                // E^T row-major [128][16]

    const int t = threadIdx.x;
    const int sub = t >> 7;          // element within block
    const int tl = t & 127;          // per-element thread id
    float* buf = smem + 2048 + sub * 2368;  // t1 / ut, row stride 132
    float* s   = buf + 2112;                // 16x16

    const int b = blockIdx.x * 2 + sub;
    const float* xb = x + (size_t)b * 16384;
    float* ob = out + (size_t)b * 16384;

    // ---- load Et to LDS (straight f4 copy, coalesced) -----------------------
    {
        f32x4* dst = (f32x4*)Et;
        const f32x4* src = (const f32x4*)wsEt;
        dst[t]       = src[t];
        dst[t + 256] = src[t + 256];
    }
    __syncthreads();

    // ---- stage 1: t1 = E @ x_b (16x128). thread = (rq, c): rows [4rq,4rq+4),
    // cols [4c,4c+4), all 128 k. Per k: 1 coalesced global f4 of x + 1 LDS
    // b128 broadcast of E^T. acc = 4 x f32x4 (16 regs). ----------------------
    {
        const int c = tl & 31;           // f4 column chunk
        const int rq = tl >> 5;          // 0..3 row quad
        const float* etp = Et + 4 * rq;
        f32x4 a0 = {0.f,0.f,0.f,0.f}, a1 = a0, a2 = a0, a3 = a0;
#pragma unroll 4
        for (int k = 0; k < 128; ++k) {
            f32x4 xv = ((const f32x4*)(xb + k * 128))[c];
            f32x4 ef = *(const f32x4*)(etp + k * 16);
            a0 += ef.x * xv;
            a1 += ef.y * xv;
            a2 += ef.z * xv;
            a3 += ef.w * xv;
        }
        float* t1 = buf;
        *(f32x4*)(t1 + (4 * rq + 0) * 132 + 4 * c) = a0;
        *(f32x4*)(t1 + (4 * rq + 1) * 132 + 4 * c) = a1;
        *(f32x4*)(t1 + (4 * rq + 2) * 132 + 4 * c) = a2;
        *(f32x4*)(t1 + (4 * rq + 3) * 132 + 4 * c) = a3;
    }
    __syncthreads();

    // ---- stage 2: s = t1 @ E^T - EPS*I. thread = (i, m2) computes s[i][m2]
    // and s[i][m2+8]. t1 row from LDS f4 (conflict-free), E rows from GLOBAL
    // (L1-resident). unroll capped to limit in-flight global loads. ----------
    {
        const int i = tl >> 3, m2 = tl & 7;
        const f32x4* t1r = (const f32x4*)(buf + i * 132);
        const f32x4* e0r = (const f32x4*)(wsE + m2 * 128);
        const f32x4* e1r = (const f32x4*)(wsE + (m2 + 8) * 128);
        float acc0 = 0.f, acc1 = 0.f;
#pragma unroll 2
        for (int q = 0; q < 32; ++q) {
            f32x4 a = t1r[q];
            f32x4 e0 = e0r[q];
            f32x4 e1v = e1r[q];
            acc0 += a.x * e0.x;  acc0 += a.y * e0.y;
            acc0 += a.z * e0.z;  acc0 += a.w * e0.w;
            acc1 += a.x * e1v.x; acc1 += a.y * e1v.y;
            acc1 += a.z * e1v.z; acc1 += a.w * e1v.w;
        }
        if (i == m2) acc0 -= SPD_EPS;
        if (i == m2 + 8) acc1 -= SPD_EPS;
        s[i * 16 + m2] = acc0;
        s[i * 16 + m2 + 8] = acc1;
    }
    __syncthreads();

    // ---- stage 3: u = D @ s, stored transposed ut[m][p] (overwrites t1). ----
    // thread p: D row p from GLOBAL (4 f4, loaded once), s rows broadcast f4
    // from LDS. 16-reg accumulator, 16 conflict-free b32 writes. -------------
    {
        const int p = tl;
        const f32x4* drow = (const f32x4*)(wsD + p * 16);
        f32x4 dq0 = drow[0], dq1 = drow[1], dq2 = drow[2], dq3 = drow[3];
        f32x4 u0 = {0.f,0.f,0.f,0.f}, u1 = u0, u2 = u0, u3 = u0;
#pragma unroll 4
        for (int i = 0; i < 16; ++i) {
            float dv = (i < 4) ? dq0[i & 3]
                     : (i < 8) ? dq1[i & 3]
                     : (i < 12) ? dq2[i & 3] : dq3[i & 3];
            const f32x4* srow = (const f32x4*)(s + i * 16);
            u0 += dv * srow[0];
            u1 += dv * srow[1];
            u2 += dv * srow[2];
            u3 += dv * srow[3];
        }
        float* ut = buf;                // t1 dead after stage 2
#pragma unroll
        for (int m = 0; m < 4; ++m) {
            ut[m * 132 + p]        = u0[m];
            ut[(m + 4) * 132 + p]  = u1[m];
            ut[(m + 8) * 132 + p]  = u2[m];
            ut[(m + 12) * 132 + p] = u3[m];
        }
    }
    __syncthreads();

    // ---- stage 4: out = u @ D^T + EPS*I. thread = (rg, cg): rows [8rg,8rg+8),
    // cols cg*4 + pass*32, 4 passes. Per m: 1 global f4 (D^T, L1) + 2 LDS b128
    // (ut, 2-way aliased = free). Plain coalesced f4 stores. ------------------
    {
        const int rg = tl >> 3;          // 0..15
        const int cg = tl & 7;           // 0..7
        const int p0 = rg * 8;
        for (int pass = 0; pass < 4; ++pass) {
            const int c0 = pass * 32 + cg * 4;
            f32x4 acc8[8];
#pragma unroll
            for (int r = 0; r < 8; ++r) acc8[r] = (f32x4){0.f, 0.f, 0.f, 0.f};
#pragma unroll 4
            for (int m = 0; m < 16; ++m) {
                f32x4 d4 = *(const f32x4*)(wsDt + m * 128 + c0);
                f32x4 ua = *(const f32x4*)(buf + m * 132 + p0);
                f32x4 ub = *(const f32x4*)(buf + m * 132 + p0 + 4);
                acc8[0] += ua.x * d4;
                acc8[1] += ua.y * d4;
                acc8[2] += ua.z * d4;
                acc8[3] += ua.w * d4;
                acc8[4] += ub.x * d4;
                acc8[5] += ub.y * d4;
                acc8[6] += ub.z * d4;
                acc8[7] += ub.w * d4;
            }
#pragma unroll
            for (int r = 0; r < 8; ++r) {
                int p = p0 + r;
                f32x4 v = acc8[r];
                int d = p - c0;
                if (d >= 0 && d < 4) v[d] += SPD_EPS;
                *(f32x4*)(ob + p * 128 + c0) = v;
            }
        }
    }
}

extern "C" void kernel_launch(void* const* d_in, const int* in_sizes, int n_in,
                              void* d_out, int out_size, void* d_ws, size_t ws_size,
                              hipStream_t stream) {
    const float* x     = (const float*)d_in[0];
    const float* wenc0 = (const float*)d_in[1];
    const float* wenc1 = (const float*)d_in[2];
    const float* wenc2 = (const float*)d_in[3];
    const float* wdec0 = (const float*)d_in[4];
    const float* wdec1 = (const float*)d_in[5];
    const float* wdec2 = (const float*)d_in[6];
    float* out = (float*)d_out;

    float* wsE  = (float*)d_ws;         // 2048 floats
    float* wsEt = wsE + 2048;           // 2048 floats
    float* wsD  = wsEt + 2048;          // 2048 floats
    float* wsDt = wsD + 2048;           // 2048 floats (32 KB total)

    const int B = in_sizes[0] / 16384;  // 2048 (even)

    setup_ED<<<16, 256, 0, stream>>>(wenc0, wenc1, wenc2, wdec0, wdec1, wdec2,
                                     wsE, wsEt, wsD, wsDt);
    spdnet_main<<<B / 2, 256, 0, stream>>>(x, wsE, wsEt, wsD, wsDt, out);
}